// Round 14
// baseline (192.489 us; speedup 1.0000x reference)
//
#include <hip/hip_runtime.h>

typedef unsigned short ushort_t;
typedef __attribute__((ext_vector_type(8))) short bf16x8;
typedef __attribute__((ext_vector_type(8))) _Float16 f16x8;
typedef __attribute__((ext_vector_type(16))) float f32x16;

#define NORMC 0.35355339059327373f   // 64^-0.25
#define DIAGC 0.0625f                // 0.5 * 64^-0.5
#define RATIO 0.0625f                // 256^-0.5
#define KEPS  1e-4f
#define AEPS  1e-6f
#define KAPPA (RATIO*KEPS)

__device__ __forceinline__ unsigned short f2bf(float f){
  unsigned u = __float_as_uint(f);
  unsigned r = (u + 0x7FFFu + ((u >> 16) & 1u)) >> 16;  // RNE
  return (unsigned short)r;
}
__device__ __forceinline__ float bf2f(unsigned short h){
  return __uint_as_float(((unsigned)h) << 16);
}
__device__ __forceinline__ unsigned enc_f(float f){
  unsigned u = __float_as_uint(f);
  return (u & 0x80000000u) ? ~u : (u | 0x80000000u);
}
__device__ __forceinline__ float dec_f(unsigned e){
  unsigned b = (e & 0x80000000u) ? (e ^ 0x80000000u) : ~e;
  return __uint_as_float(b);
}
__device__ __forceinline__ unsigned short h2u(_Float16 h){
  union { _Float16 h; unsigned short u; } c; c.h = h; return c.u;
}
__device__ __forceinline__ unsigned pk2h(float a, float b){
  return (unsigned)h2u((_Float16)a) | ((unsigned)h2u((_Float16)b) << 16);
}

// K0: proj -> fp16 (NORMC-scaled), layout [m][d]; init global-max slot
__global__ void k_prep(const float* __restrict__ proj, ushort_t* __restrict__ pjh,
                       unsigned* __restrict__ kmax){
  int t = threadIdx.x;   // m
  if (t == 0) *kmax = 0u;
  for (int d = 0; d < 64; ++d){
    float val = NORMC * proj[t*64 + d];
    pjh[t*64 + d] = h2u((_Float16)val);
  }
}

// K_FQ: q-feature GEMM only. 512 blocks, 8 waves. Writes qf linear [row][m].
__launch_bounds__(512, 4)
__global__ void k_featQ(const float* __restrict__ q, const ushort_t* __restrict__ pjh,
                        ushort_t* __restrict__ qf)
{
  extern __shared__ char sm[];
  char* Bp = sm;
  char* Xh = sm + 32768;
  char* Xl = sm + 49152;
  float* dsm = (float*)(sm + 65536);
  float* rmx = (float*)(sm + 66048);

  int tid = threadIdx.x;
  int w   = tid >> 6;
  int wr  = w & 3;
  int wc  = w >> 2;
  int lane= tid & 63;
  int l31 = lane & 31;
  int half= lane >> 5;
  int tile = (int)blockIdx.x;
  int row0 = tile * 128;

  for (int i = tid; i < 2048; i += 512){
    int m = i >> 3, c8 = i & 7;
    int rgn = ((m>>5)*4 + (c8>>1))*2 + (c8&1);
    int slot = (m & 31) ^ ((rgn & 7) << 2);
    *(uint4*)(Bp + rgn*512 + slot*16) = *(const uint4*)(pjh + m*64 + c8*8);
  }
  #pragma unroll
  for (int it = 0; it < 4; ++it){
    int g = it*512 + tid;
    int row = g >> 4, c4 = g & 15;
    float4 xv = *(const float4*)(q + (size_t)(row0+row)*64 + c4*4);
    _Float16 h0=(_Float16)xv.x, h1=(_Float16)xv.y, h2=(_Float16)xv.z, h3=(_Float16)xv.w;
    float l0 = xv.x-(float)h0, l1 = xv.y-(float)h1, l2 = xv.z-(float)h2, l3 = xv.w-(float)h3;
    int rgn = ((row>>5)*4 + (c4>>2))*2 + ((c4>>1)&1);
    int off = rgn*512 + (((row&31) ^ ((c4>>1)<<2)))*16 + (c4&1)*8;
    uint2 ph; ph.x = (unsigned)h2u(h0)|((unsigned)h2u(h1)<<16);
              ph.y = (unsigned)h2u(h2)|((unsigned)h2u(h3)<<16);
    uint2 pl; pl.x = pk2h(l0,l1); pl.y = pk2h(l2,l3);
    *(uint2*)(Xh + off) = ph;
    *(uint2*)(Xl + off) = pl;
    float ssq = xv.x*xv.x + xv.y*xv.y + xv.z*xv.z + xv.w*xv.w;
    ssq += __shfl_xor(ssq, 1); ssq += __shfl_xor(ssq, 2);
    ssq += __shfl_xor(ssq, 4); ssq += __shfl_xor(ssq, 8);
    if ((tid & 15) == 0) dsm[row] = ssq;
  }
  __syncthreads();

  f16x8 ah[4], al[4];
  #pragma unroll
  for (int ks = 0; ks < 4; ++ks){
    int rgn = (wr*4+ks)*2+half;
    int off = rgn*512 + ((l31 ^ ((2*ks+half)<<2)))*16;
    ah[ks] = *(const f16x8*)(Xh + off);
    al[ks] = *(const f16x8*)(Xl + off);
  }
  f32x16 acc[4];
  #pragma unroll
  for (int ct=0; ct<4; ++ct){
    #pragma unroll
    for (int r=0; r<16; ++r) acc[ct][r] = 0.f;
  }
  #pragma unroll
  for (int ks = 0; ks < 4; ++ks){
    #pragma unroll
    for (int ct=0; ct<4; ++ct){
      int ctg = wc*4 + ct;
      int rgn = (ctg*4+ks)*2+half;
      f16x8 bv = *(const f16x8*)(Bp + rgn*512 + ((l31 ^ ((2*ks+half)<<2)))*16);
      acc[ct] = __builtin_amdgcn_mfma_f32_32x32x16_f16(ah[ks], bv, acc[ct], 0, 0, 0);
      acc[ct] = __builtin_amdgcn_mfma_f32_32x32x16_f16(al[ks], bv, acc[ct], 0, 0, 0);
    }
  }
  {
    float rmax[16];
    #pragma unroll
    for (int r=0; r<16; ++r){
      float mx = acc[0][r];
      #pragma unroll
      for (int ct=1; ct<4; ++ct) mx = fmaxf(mx, acc[ct][r]);
      #pragma unroll
      for (int s=1; s<32; s<<=1) mx = fmaxf(mx, __shfl_xor(mx, s));
      rmax[r] = mx;
    }
    if (l31 == 0){
      #pragma unroll
      for (int r=0; r<16; ++r)
        rmx[wc*128 + 32*wr + (r&3) + 8*(r>>2) + 4*half] = rmax[r];
    }
  }
  __syncthreads();

  float dgv[16], stv[16];
  #pragma unroll
  for (int r=0; r<16; ++r){
    int lrow = 32*wr + (r&3) + 8*(r>>2) + 4*half;
    dgv[r] = DIAGC * dsm[lrow];
    stv[r] = fmaxf(rmx[lrow], rmx[128+lrow]);
  }

  char* ob = sm;
  #pragma unroll
  for (int r=0; r<16; ++r){
    int lrow = 32*wr + (r&3) + 8*(r>>2) + 4*half;
    #pragma unroll
    for (int ct=0; ct<4; ++ct){
      int col = wc*128 + ct*32 + l31;
      float e = __expf(acc[ct][r] - dgv[r] - stv[r]);
      *(ushort_t*)(ob + lrow*512 + ((col*2) ^ ((lrow&15)<<4))) = f2bf(RATIO*(e + KEPS));
    }
  }
  __syncthreads();
  ushort_t* dst = qf + (size_t)row0*256;
  for (int i = tid; i < 4096; i += 512){
    int row = i >> 5, s = i & 31;
    uint4 d = *(const uint4*)(ob + row*512 + ((s*16) ^ ((row&15)<<4)));
    *(uint4*)(dst + (size_t)row*256 + ((s ^ (row&15)))*8) = d;
  }
}

// K_A: k-feature GEMM + per-chunk sums (unchanged, verified).
__launch_bounds__(512, 2)
__global__ void k_chunkF(const float* __restrict__ kk, const float* __restrict__ v,
                         const ushort_t* __restrict__ pjh,
                         ushort_t* __restrict__ kfp, float* __restrict__ Zl,
                         float* __restrict__ Sl, float* __restrict__ vsb,
                         unsigned* __restrict__ kmax, float* __restrict__ lmArr)
{
  extern __shared__ char sm[];
  char* Bp = sm;
  char* Xh = sm + 32768;
  char* Xl = sm + 49152;
  char* ob = sm;
  char* kT = sm + 65536;
  char* vT = sm + 131072;
  float* dsm  = (float*)(sm + 147456);
  float* wred = (float*)(sm + 147968);

  int tid = threadIdx.x;
  int w   = tid >> 6;
  int wr  = w & 3;
  int wc  = w >> 2;
  int lane= tid & 63;
  int l31 = lane & 31;
  int half= lane >> 5;
  int cb  = (int)blockIdx.x;
  int bh  = cb >> 5, j = cb & 31;
  int row0 = bh*4096 + j*128;

  for (int i = tid; i < 2048; i += 512){
    int m = i >> 3, c8 = i & 7;
    int rgn = ((m>>5)*4 + (c8>>1))*2 + (c8&1);
    int slot = (m & 31) ^ ((rgn & 7) << 2);
    *(uint4*)(Bp + rgn*512 + slot*16) = *(const uint4*)(pjh + m*64 + c8*8);
  }
  #pragma unroll
  for (int it = 0; it < 4; ++it){
    int g = it*512 + tid;
    int row = g >> 4, c4 = g & 15;
    float4 xv = *(const float4*)(kk + (size_t)(row0+row)*64 + c4*4);
    _Float16 h0=(_Float16)xv.x, h1=(_Float16)xv.y, h2=(_Float16)xv.z, h3=(_Float16)xv.w;
    float l0 = xv.x-(float)h0, l1 = xv.y-(float)h1, l2 = xv.z-(float)h2, l3 = xv.w-(float)h3;
    int rgn = ((row>>5)*4 + (c4>>2))*2 + ((c4>>1)&1);
    int off = rgn*512 + (((row&31) ^ ((c4>>1)<<2)))*16 + (c4&1)*8;
    uint2 ph; ph.x = (unsigned)h2u(h0)|((unsigned)h2u(h1)<<16);
              ph.y = (unsigned)h2u(h2)|((unsigned)h2u(h3)<<16);
    uint2 pl; pl.x = pk2h(l0,l1); pl.y = pk2h(l2,l3);
    *(uint2*)(Xh + off) = ph;
    *(uint2*)(Xl + off) = pl;
    float ssq = xv.x*xv.x + xv.y*xv.y + xv.z*xv.z + xv.w*xv.w;
    ssq += __shfl_xor(ssq, 1); ssq += __shfl_xor(ssq, 2);
    ssq += __shfl_xor(ssq, 4); ssq += __shfl_xor(ssq, 8);
    if ((tid & 15) == 0) dsm[row] = ssq;
  }
  {
    int e = tid & 63, c0 = tid >> 6;
    int swz = (e & 15) << 4;
    #pragma unroll
    for (int u=0; u<16; ++u){
      int c = c0 + u*8;
      *(ushort_t*)(vT + e*256 + ((c*2) ^ swz)) = f2bf(v[(size_t)(row0+c)*64 + e]);
    }
  }
  __syncthreads();

  f16x8 ah[4], al[4];
  #pragma unroll
  for (int ks = 0; ks < 4; ++ks){
    int rgn = (wr*4+ks)*2+half;
    int off = rgn*512 + ((l31 ^ ((2*ks+half)<<2)))*16;
    ah[ks] = *(const f16x8*)(Xh + off);
    al[ks] = *(const f16x8*)(Xl + off);
  }
  f32x16 acc[4];
  #pragma unroll
  for (int ct=0; ct<4; ++ct){
    #pragma unroll
    for (int r=0; r<16; ++r) acc[ct][r] = 0.f;
  }
  #pragma unroll
  for (int ks = 0; ks < 4; ++ks){
    #pragma unroll
    for (int ct=0; ct<4; ++ct){
      int ctg = wc*4 + ct;
      int rgn = (ctg*4+ks)*2+half;
      f16x8 bv = *(const f16x8*)(Bp + rgn*512 + ((l31 ^ ((2*ks+half)<<2)))*16);
      acc[ct] = __builtin_amdgcn_mfma_f32_32x32x16_f16(ah[ks], bv, acc[ct], 0, 0, 0);
      acc[ct] = __builtin_amdgcn_mfma_f32_32x32x16_f16(al[ks], bv, acc[ct], 0, 0, 0);
    }
  }
  {
    float wm = acc[0][0];
    #pragma unroll
    for (int ct=0; ct<4; ++ct){
      #pragma unroll
      for (int r=0; r<16; ++r) wm = fmaxf(wm, acc[ct][r]);
    }
    #pragma unroll
    for (int s=1; s<32; s<<=1) wm = fmaxf(wm, __shfl_xor(wm, s));
    wm = fmaxf(wm, __shfl_xor(wm, 32));
    if (lane == 0) wred[w] = wm;
  }
  __syncthreads();
  float lmb = wred[0];
  #pragma unroll
  for (int i=1;i<8;++i) lmb = fmaxf(lmb, wred[i]);
  if (tid == 0){
    lmArr[cb] = lmb;
    atomicMax(kmax, enc_f(lmb));
  }
  float dgv[16];
  #pragma unroll
  for (int r=0; r<16; ++r)
    dgv[r] = DIAGC * dsm[32*wr + (r&3) + 8*(r>>2) + 4*half];

  #pragma unroll
  for (int ct=0; ct<4; ++ct){
    int m = wc*128 + ct*32 + l31;
    int swm = (m & 15) << 4;
    #pragma unroll
    for (int g=0; g<4; ++g){
      unsigned pk0=0, pk1=0;
      #pragma unroll
      for (int rr=0; rr<4; ++rr){
        int r = g*4 + rr;
        int c = 32*wr + rr + 8*g + 4*half;
        float e = __expf(acc[ct][r] - dgv[r] - lmb);
        unsigned b = f2bf(e);
        if (rr < 2) pk0 |= b << (16*rr); else pk1 |= b << (16*(rr-2));
        *(ushort_t*)(ob + c*512 + ((m*2) ^ ((c&15)<<4))) = (ushort_t)b;
      }
      int c0 = 32*wr + 8*g + 4*half;
      *(uint2*)(kT + m*256 + ((c0*2) ^ swm)) = make_uint2(pk0, pk1);
    }
  }
  __syncthreads();

  f32x16 accS[2], accz, avs[2];
  #pragma unroll
  for (int et=0;et<2;++et){
    #pragma unroll
    for (int r=0;r<16;++r){ accS[et][r]=0.f; avs[et][r]=0.f; }
  }
  #pragma unroll
  for (int r=0;r<16;++r) accz[r]=0.f;
  bf16x8 onesB, onesA;
  #pragma unroll
  for (int i=0;i<8;++i){
    onesB[i] = (l31==0) ? (short)0x3F80 : (short)0;
    onesA[i] = (short)0x3F80;
  }
  int erow = (w&1)*32 + l31;
  int mc0  = ((w>>1)*2 + 0)*32 + l31;
  int mc1  = ((w>>1)*2 + 1)*32 + l31;
  int mrow = 32*w + l31;
  #pragma unroll
  for (int ks=0; ks<8; ++ks){
    int koff = ks*32 + half*16;
    bf16x8 afv = *(const bf16x8*)(vT + erow*256 + (koff ^ ((erow&15)<<4)));
    bf16x8 bk0 = *(const bf16x8*)(kT + mc0*256 + (koff ^ ((mc0&15)<<4)));
    bf16x8 bk1 = *(const bf16x8*)(kT + mc1*256 + (koff ^ ((mc1&15)<<4)));
    bf16x8 afk = *(const bf16x8*)(kT + mrow*256 + (koff ^ ((mrow&15)<<4)));
    accS[0] = __builtin_amdgcn_mfma_f32_32x32x16_bf16(afv, bk0, accS[0], 0, 0, 0);
    accS[1] = __builtin_amdgcn_mfma_f32_32x32x16_bf16(afv, bk1, accS[1], 0, 0, 0);
    accz    = __builtin_amdgcn_mfma_f32_32x32x16_bf16(afk, onesB, accz, 0, 0, 0);
    if (w == 0){
      bf16x8 bv1 = *(const bf16x8*)(vT + (32+l31)*256 + (koff ^ (((32+l31)&15)<<4)));
      avs[0] = __builtin_amdgcn_mfma_f32_32x32x16_bf16(onesA, afv, avs[0], 0, 0, 0);
      avs[1] = __builtin_amdgcn_mfma_f32_32x32x16_bf16(onesA, bv1, avs[1], 0, 0, 0);
    }
  }
  #pragma unroll
  for (int r=0; r<16; ++r){
    int e = (w&1)*32 + (r&3) + 8*(r>>2) + 4*half;
    Sl[(size_t)cb*16384 + (size_t)e*256 + ((w>>1)*2+0)*32 + l31] = accS[0][r];
    Sl[(size_t)cb*16384 + (size_t)e*256 + ((w>>1)*2+1)*32 + l31] = accS[1][r];
  }
  if (l31 == 0){
    #pragma unroll
    for (int r=0; r<16; ++r){
      int m = 32*w + (r&3) + 8*(r>>2) + 4*half;
      Zl[(size_t)cb*256 + m] = accz[r];
    }
  }
  if (w == 0 && half == 0){
    vsb[(size_t)cb*64 + l31]      = avs[0][0];
    vsb[(size_t)cb*64 + 32 + l31] = avs[1][0];
  }
  {
    ushort_t* dst = kfp + (size_t)row0*256;
    for (int i = tid; i < 4096; i += 512){
      int row = i >> 5, s = i & 31;
      uint4 d = *(const uint4*)(ob + row*512 + ((s*16) ^ ((row&15)<<4)));
      *(uint4*)(dst + (size_t)row*256 + ((s ^ (row&15)))*8) = d;
    }
  }
}

// K4: scan with alpha/kappa correction (unchanged).
__launch_bounds__(256)
__global__ void k_scan(float* __restrict__ Zl, const float* __restrict__ Sl,
                       const float* __restrict__ vsb, const float* __restrict__ lmArr,
                       const unsigned* __restrict__ kmax,
                       ushort_t* __restrict__ S0b,
                       float* __restrict__ outZ, float* __restrict__ outSt){
  float gm = dec_f(*kmax);
  int t = threadIdx.x;
  int bh = blockIdx.x / 65;
  int s  = blockIdx.x % 65;
  if (s == 64){
    size_t base = (size_t)(bh*32)*256 + t;
    float rz = 0.f;
    #pragma unroll
    for (int j0=0;j0<32;j0+=8){
      float x[8];
      #pragma unroll
      for (int u=0;u<8;++u){
        int cbx = bh*32 + j0 + u;
        float a = RATIO * __expf(lmArr[cbx] - gm);
        x[u] = fmaf(a, Zl[base + (size_t)(j0+u)*256], KAPPA*128.f);
      }
      #pragma unroll
      for (int u=0;u<8;++u){ Zl[base + (size_t)(j0+u)*256] = rz; rz += x[u]; }
    }
    outZ[(size_t)bh*256 + t] = rz;
  } else {
    size_t base = (size_t)(bh*32)*16384 + (size_t)s*256 + t;
    float rs = 0.f;
    #pragma unroll
    for (int j0=0;j0<32;j0+=8){
      float x[8];
      #pragma unroll
      for (int u=0;u<8;++u){
        int cbx = bh*32 + j0 + u;
        float a = RATIO * __expf(lmArr[cbx] - gm);
        x[u] = fmaf(a, Sl[base + (size_t)(j0+u)*16384], KAPPA * vsb[(size_t)cbx*64 + s]);
      }
      #pragma unroll
      for (int u=0;u<8;++u){
        S0b[(size_t)(bh*32 + j0+u)*16384 + (size_t)s*256 + t] = f2bf(rs);
        rs += x[u];
      }
    }
    outSt[(size_t)bh*16384 + (size_t)s*256 + t] = rs;
  }
}

// K_TR: outSt [bh][e][m] -> outS [bh][m][e] (unchanged).
__launch_bounds__(256)
__global__ void k_tr(const float* __restrict__ outSt, float* __restrict__ outS){
  __shared__ float tl[64][65];
  int tid = threadIdx.x;
  int bh = blockIdx.x >> 2, mt = blockIdx.x & 3;
  int m0 = mt*64;
  for (int i = tid; i < 4096; i += 256){
    int e = i >> 6, m = i & 63;
    tl[e][m] = outSt[(size_t)bh*16384 + (size_t)e*256 + m0 + m];
  }
  __syncthreads();
  for (int i = tid; i < 4096; i += 256){
    int m = i >> 6, e = i & 63;
    outS[(size_t)bh*16384 + (size_t)(m0+m)*64 + e] = tl[e][m];
  }
}

// K_B v2: two-pass to cap live AGPRs at 48 -> fits 128-reg budget -> 2 blocks/CU.
// Pass A: acc2 = qf*S0, accQ = qf*[z0|ones] (32 AGPR). qz/qfs -> LDS; accQ freed.
// Pass B: accA = qf*kfpre^T triangle (32 AGPR) with acc2 (16) held.
// Epilogue: alpha-correct A (qfs from LDS), rowsums, A*v, divide (qz from LDS).
__launch_bounds__(512, 4)
__global__ void k_out(const ushort_t* __restrict__ qf, const ushort_t* __restrict__ kfp,
                      const float* __restrict__ v, const ushort_t* __restrict__ S0b,
                      const float* __restrict__ Zp, const float* __restrict__ lmArr,
                      const unsigned* __restrict__ kmax, float* __restrict__ outO)
{
  extern __shared__ char sm[];
  char* Ab   = sm;                      // [128][256B] bf16, swz ^((r&15)<<4)
  char* qft  = sm + 32768;              // [128 c][128B m-tile], swz ^((c&7)<<4)
  char* vTb  = sm + 32768;              // A*v phase alias: [64 e][256B], swz ^((e&15)<<4)
  char* ktb  = sm + 49152;              // [128 i][128B m-tile], swz ^((i&7)<<4)
  char* s0t  = sm + 65536;              // [64 e][128B m-tile], swz ^((e&7)<<4)
  float* rsc = (float*)(sm + 73728);    // [2][128]
  ushort_t* z0b = (ushort_t*)(sm + 74752); // [256] bf16(Z0+eps)
  float* qzl = (float*)(sm + 75264);    // [128] qf·(Z0+eps)
  float* qfl = (float*)(sm + 75776);    // [128] row-sums of qf
  // total 76288 B -> 2 blocks/CU by LDS

  int tid = threadIdx.x;
  int w   = tid >> 6;
  int wr  = w & 3;
  int wc  = w >> 2;
  int lane= tid & 63;
  int l31 = lane & 31;
  int half= lane >> 5;
  int pb  = (int)blockIdx.x;
  int bh  = pb >> 5, j = pb & 31;
  int row0 = bh*4096 + j*128;
  size_t qbase = (size_t)row0*256;

  float gmv = dec_f(*kmax);
  float alpha = RATIO * __expf(lmArr[pb] - gmv);

  if (tid < 256) z0b[tid] = f2bf(Zp[(size_t)pb*256 + tid] + AEPS);

  // staging addressing (static per thread)
  int rr0 = (tid*2)   >> 3, c80 = (tid*2)   & 7;
  int rr1 = (tid*2+1) >> 3, c81 = (tid*2+1) & 7;
  int se  = tid >> 3,  sc8 = tid & 7;
  int dsw0 = (c80*16) ^ ((rr0&7)<<4);
  int dsw1 = (c81*16) ^ ((rr1&7)<<4);
  int dsws = (sc8*16) ^ ((se&7)<<4);
  int arow = 32*wr + l31;

  // ================= Pass A: acc2 = qf*S0, accQ = qf*[z0|ones] =================
  f32x16 acc2, accQ;
  #pragma unroll
  for (int r=0;r<16;++r){ acc2[r] = 0.f; accQ[r] = 0.f; }
  {
    uint4 pq0, pq1, ps0;
    pq0 = *(const uint4*)(qf  + qbase + (size_t)rr0*256 + c80*8);
    pq1 = *(const uint4*)(qf  + qbase + (size_t)rr1*256 + c81*8);
    ps0 = *(const uint4*)(S0b + (size_t)pb*16384 + (size_t)se*256 + sc8*8);
    #pragma unroll
    for (int mt=0; mt<4; ++mt){
      int m0 = mt*64;
      __syncthreads();
      *(uint4*)(qft + rr0*128 + dsw0) = pq0;
      *(uint4*)(qft + rr1*128 + dsw1) = pq1;
      *(uint4*)(s0t + se*128  + dsws) = ps0;
      __syncthreads();
      if (mt < 3){
        int mn = (mt+1)*64;
        pq0 = *(const uint4*)(qf  + qbase + (size_t)rr0*256 + mn + c80*8);
        pq1 = *(const uint4*)(qf  + qbase + (size_t)rr1*256 + mn + c81*8);
        ps0 = *(const uint4*)(S0b + (size_t)pb*16384 + (size_t)se*256 + mn + sc8*8);
      }
      #pragma unroll
      for (int ks=0;ks<4;++ks){
        int ko = ks*32 + half*16;
        bf16x8 af = *(const bf16x8*)(qft + arow*128 + (ko ^ ((arow&7)<<4)));
        {
          int er = wc*32 + l31;
          bf16x8 bS = *(const bf16x8*)(s0t + er*128 + (ko ^ ((er&7)<<4)));
          acc2 = __builtin_amdgcn_mfma_f32_32x32x16_bf16(af, bS, acc2, 0, 0, 0);
        }
        {
          bf16x8 zb = {};
          if (l31 == 0) zb = *(const bf16x8*)((const char*)z0b + m0*2 + ko);
          if (l31 == 1){
            #pragma unroll
            for (int i2=0;i2<8;++i2) zb[i2] = (short)0x3F80;
          }
          accQ = __builtin_amdgcn_mfma_f32_32x32x16_bf16(af, zb, accQ, 0, 0, 0);
        }
      }
    }
  }
  // extract qz (col 0) / qfs (col 1) per row -> LDS; accQ dies here
  #pragma unroll
  for (int r=0;r<16;++r){
    float qz  = __shfl(accQ[r], half*32 + 0);
    float qfs = __shfl(accQ[r], half*32 + 1);
    if (wc == 0 && l31 == 0){
      int grow = 32*wr + (r&3) + 8*(r>>2) + 4*half;
      qzl[grow] = qz;
      qfl[grow] = qfs;
    }
  }

  // ================= Pass B: accA = qf*kfpre^T (triangle) =================
  f32x16 accA[2];
  #pragma unroll
  for (int ct2=0;ct2<2;++ct2){
    #pragma unroll
    for (int r=0;r<16;++r) accA[ct2][r] = 0.f;
  }
  {
    uint4 pq0, pq1, pk0v, pk1v;
    pq0  = *(const uint4*)(qf  + qbase + (size_t)rr0*256 + c80*8);
    pq1  = *(const uint4*)(qf  + qbase + (size_t)rr1*256 + c81*8);
    pk0v = *(const uint4*)(kfp + qbase + (size_t)rr0*256 + c80*8);
    pk1v = *(const uint4*)(kfp + qbase + (size_t)rr1*256 + c81*8);
    #pragma unroll
    for (int mt=0; mt<4; ++mt){
      __syncthreads();
      *(uint4*)(qft + rr0*128 + dsw0) = pq0;
      *(uint4*)(qft + rr1*128 + dsw1) = pq1;
      *(uint4*)(ktb + rr0*128 + dsw0) = pk0v;
      *(uint4*)(ktb + rr1*128 + dsw1) = pk1v;
      __syncthreads();
      if (mt < 3){
        int mn = (mt+1)*64;
        pq0  = *(const uint4*)(qf  + qbase + (size_t)rr0*256 + mn + c80*8);
        pq1  = *(const uint4*)(qf  + qbase + (size_t)rr1*256 + mn + c81*8);
        pk0v = *(const uint4*)(kfp + qbase + (size_t)rr0*256 + mn + c80*8);
        pk1v = *(const uint4*)(kfp + qbase + (size_t)rr1*256 + mn + c81*8);
      }
      #pragma unroll
      for (int ks=0;ks<4;++ks){
        int ko = ks*32 + half*16;
        bf16x8 af = *(const bf16x8*)(qft + arow*128 + (ko ^ ((arow&7)<<4)));
        #pragma unroll
        for (int ct2=0;ct2<2;++ct2){
          int c = wc*2 + ct2;
          if (c <= wr){
            int br = c*32 + l31;
            bf16x8 bk = *(const bf16x8*)(ktb + br*128 + (ko ^ ((br&7)<<4)));
            accA[ct2] = __builtin_amdgcn_mfma_f32_32x32x16_bf16(af, bk, accA[ct2], 0, 0, 0);
          }
        }
      }
    }
  }

  // mask + alpha-correct A (qfs from LDS), rowsums, write Ab bf16
  {
    float p[16];
    #pragma unroll
    for (int r=0;r<16;++r) p[r]=0.f;
    #pragma unroll
    for (int r=0;r<16;++r){
      int grow = 32*wr + (r&3) + 8*(r>>2) + 4*half;
      float qfs = qfl[grow];
      #pragma unroll
      for (int ct2=0;ct2<2;++ct2){
        int c = wc*2 + ct2;
        if (c <= wr){
          int col = c*32 + l31;
          float mval = (col <= grow) ? fmaf(alpha, accA[ct2][r], KAPPA*qfs) : 0.f;
          p[r] += mval;
          *(ushort_t*)(Ab + grow*256 + ((col*2) ^ ((grow&15)<<4))) = f2bf(mval);
        }
      }
    }
    #pragma unroll
    for (int s2=1;s2<32;s2<<=1){
      #pragma unroll
      for (int r=0;r<16;++r) p[r] += __shfl_xor(p[r], s2);
    }
    if (l31 == 0){
      #pragma unroll
      for (int r=0;r<16;++r)
        rsc[wc*128 + 32*wr + (r&3) + 8*(r>>2) + 4*half] = p[r];
    }
  }
  __syncthreads();

  // stage vTb from global (over dead qft/ktb)
  {
    int ve = tid & 63, vc0 = tid >> 6;
    int swz = (ve & 15) << 4;
    #pragma unroll
    for (int u=0; u<16; ++u){
      int c = vc0 + u*8;
      float vv = v[(size_t)(row0 + c)*64 + ve];
      *(ushort_t*)(vTb + ve*256 + ((c*2) ^ swz)) = f2bf(vv);
    }
  }
  __syncthreads();

  // A*v (triangle over ks)
  #pragma unroll
  for (int ks=0; ks<8; ++ks){
    if (ks <= 2*wr + 1){
      bf16x8 af = *(const bf16x8*)(Ab + arow*256 + ((ks*32 + half*16) ^ ((arow&15)<<4)));
      int er = wc*32 + l31;
      bf16x8 bv = *(const bf16x8*)(vTb + er*256 + ((ks*32 + half*16) ^ ((er&15)<<4)));
      acc2 = __builtin_amdgcn_mfma_f32_32x32x16_bf16(af, bv, acc2, 0, 0, 0);
    }
  }

  // epilogue: divide & store (qz from LDS)
  #pragma unroll
  for (int r=0;r<16;++r){
    int grow = 32*wr + (r&3) + 8*(r>>2) + 4*half;
    float dv = 1.0f / (rsc[grow] + rsc[128+grow] + qzl[grow]);
    outO[(size_t)(row0+grow)*64 + wc*32 + l31] = acc2[r] * dv;
  }
}

extern "C" void kernel_launch(void* const* d_in, const int* in_sizes, int n_in,
                              void* d_out, int out_size, void* d_ws, size_t ws_size,
                              hipStream_t stream){
  (void)in_sizes; (void)n_in; (void)out_size; (void)ws_size;
  const float* q    = (const float*)d_in[0];
  const float* k    = (const float*)d_in[1];
  const float* v    = (const float*)d_in[2];
  const float* proj = (const float*)d_in[3];

  char* ws = (char*)d_ws;
  unsigned* kmax = (unsigned*)ws;                          // @0
  float*    lmA  = (float*)(ws + 256);                     // 2048 B
  ushort_t* pjh  = (ushort_t*)(ws + 4096);                 // 32768 B
  ushort_t* kfp  = (ushort_t*)(ws + 65792);                // 33,554,432
  float*    Zl   = (float*)(ws + 33620224);                // 524,288
  float*    Sl   = (float*)(ws + 34144512);                // 33,554,432 ([cb][e][m])
  ushort_t* S0b  = (ushort_t*)(ws + 67698944);             // 16,777,216 ([pb][e][m])
  float*    vsb  = (float*)(ws + 84476160);                // 131,072
  float*    oSt  = (float*)(ws + 84607232);                // 4,194,304 ([bh][e][m])
  ushort_t* qfb  = (ushort_t*)(ws + 88801536);             // 33,554,432

  float* outO = (float*)d_out;
  float* outZ = outO + (size_t)2*8*4096*64;
  float* outS = outZ + 2*8*256;

  hipFuncSetAttribute((const void*)k_featQ,  hipFuncAttributeMaxDynamicSharedMemorySize, 67072);
  hipFuncSetAttribute((const void*)k_chunkF, hipFuncAttributeMaxDynamicSharedMemorySize, 148480);
  hipFuncSetAttribute((const void*)k_out,    hipFuncAttributeMaxDynamicSharedMemorySize, 76288);

  k_prep  <<<1,     256, 0, stream>>>(proj, pjh, kmax);
  k_featQ <<<512,   512, 67072, stream>>>(q, pjh, qfb);
  k_chunkF<<<512,   512, 148480, stream>>>(k, v, pjh, kfp, Zl, Sl, vsb, kmax, lmA);
  k_scan  <<<16*65, 256, 0, stream>>>(Zl, Sl, vsb, lmA, kmax, S0b, outZ, oSt);
  k_tr    <<<64,    256, 0, stream>>>(oSt, outS);
  k_out   <<<512,   512, 76288, stream>>>(qfb, kfp, v, S0b, Zl, lmA, kmax, outO);
}

// Round 15
// 93.955 us; speedup vs baseline: 2.0487x; 2.0487x over previous
//
#include <hip/hip_runtime.h>

typedef unsigned short ushort_t;
typedef __attribute__((ext_vector_type(8))) short bf16x8;
typedef __attribute__((ext_vector_type(8))) _Float16 f16x8;
typedef __attribute__((ext_vector_type(16))) float f32x16;

#define NORMC 0.35355339059327373f   // 64^-0.25
#define DIAGC 0.0625f                // 0.5 * 64^-0.5
#define RATIO 0.0625f                // 256^-0.5
#define KEPS  1e-4f
#define AEPS  1e-6f
#define KAPPA (RATIO*KEPS)

__device__ __forceinline__ unsigned short f2bf(float f){
  unsigned u = __float_as_uint(f);
  unsigned r = (u + 0x7FFFu + ((u >> 16) & 1u)) >> 16;  // RNE
  return (unsigned short)r;
}
__device__ __forceinline__ float bf2f(unsigned short h){
  return __uint_as_float(((unsigned)h) << 16);
}
__device__ __forceinline__ unsigned enc_f(float f){
  unsigned u = __float_as_uint(f);
  return (u & 0x80000000u) ? ~u : (u | 0x80000000u);
}
__device__ __forceinline__ float dec_f(unsigned e){
  unsigned b = (e & 0x80000000u) ? (e ^ 0x80000000u) : ~e;
  return __uint_as_float(b);
}
__device__ __forceinline__ unsigned short h2u(_Float16 h){
  union { _Float16 h; unsigned short u; } c; c.h = h; return c.u;
}
__device__ __forceinline__ unsigned pk2h(float a, float b){
  return (unsigned)h2u((_Float16)a) | ((unsigned)h2u((_Float16)b) << 16);
}
// corrected-kf transform: bf16(alpha*bf2f(x)+kappa) for both halves of a packed word
__device__ __forceinline__ unsigned cvt2(unsigned wrd, float alpha){
  float lo = bf2f((ushort_t)(wrd & 0xffffu));
  float hi = bf2f((ushort_t)(wrd >> 16));
  return (unsigned)f2bf(fmaf(alpha, lo, KAPPA)) |
         ((unsigned)f2bf(fmaf(alpha, hi, KAPPA)) << 16);
}

// K0: proj -> fp16 (NORMC-scaled), layout [m][d]; init global-max slot
__global__ void k_prep(const float* __restrict__ proj, ushort_t* __restrict__ pjh,
                       unsigned* __restrict__ kmax){
  int t = threadIdx.x;   // m
  if (t == 0) *kmax = 0u;
  for (int d = 0; d < 64; ++d){
    float val = NORMC * proj[t*64 + d];
    pjh[t*64 + d] = h2u((_Float16)val);
  }
}

// K1 (fused, MFMA fp16 2-term), 8 waves: wave w -> rows 32*(w&3), cols 128*(w>>2).
// blocks 0..511 -> q (store qf, row-max stab); 512..1023 -> k (store kfpre, lm, atomicMax gm)
__launch_bounds__(512, 4)
__global__ void k_feat(const float* __restrict__ q, const float* __restrict__ k,
                       const ushort_t* __restrict__ pjh,
                       ushort_t* __restrict__ qf, ushort_t* __restrict__ kfp,
                       unsigned* __restrict__ kmax, float* __restrict__ lmArr)
{
  extern __shared__ char sm[];
  char* Bp = sm;                        // 32768: 64 regions x 32 slots x 16B, slot ^= (rgn&7)<<2
  char* Xh = sm + 32768;                // 16384: 32 regions
  char* Xl = sm + 49152;                // 16384
  float* dsm  = (float*)(sm + 65536);   // [128]
  float* rmx  = (float*)(sm + 66048);   // [2][128]
  float* wred = (float*)(sm + 67072);   // [8]

  int tid = threadIdx.x;
  int w   = tid >> 6;
  int wr  = w & 3;       // row group
  int wc  = w >> 2;      // col half
  int lane= tid & 63;
  int l31 = lane & 31;
  int half= lane >> 5;

  bool isQ = (blockIdx.x < 512);
  int tile = isQ ? (int)blockIdx.x : (int)blockIdx.x - 512;
  const float* src = isQ ? q : k;
  int row0 = tile * 128;

  // stage proj frags (coalesced, XOR-swizzled slots)
  for (int i = tid; i < 2048; i += 512){
    int m = i >> 3, c8 = i & 7;
    int rgn = ((m>>5)*4 + (c8>>1))*2 + (c8&1);
    int slot = (m & 31) ^ ((rgn & 7) << 2);
    *(uint4*)(Bp + rgn*512 + slot*16) = *(const uint4*)(pjh + m*64 + c8*8);
  }
  // stage x frags (coalesced float4 -> fp16 hi/lo), per-row sum(x^2)
  #pragma unroll
  for (int it = 0; it < 4; ++it){
    int g = it*512 + tid;
    int row = g >> 4, c4 = g & 15;
    float4 xv = *(const float4*)(src + (size_t)(row0+row)*64 + c4*4);
    _Float16 h0=(_Float16)xv.x, h1=(_Float16)xv.y, h2=(_Float16)xv.z, h3=(_Float16)xv.w;
    float l0 = xv.x-(float)h0, l1 = xv.y-(float)h1, l2 = xv.z-(float)h2, l3 = xv.w-(float)h3;
    int rgn = ((row>>5)*4 + (c4>>2))*2 + ((c4>>1)&1);
    int off = rgn*512 + (((row&31) ^ ((c4>>1)<<2)))*16 + (c4&1)*8;
    uint2 ph; ph.x = (unsigned)h2u(h0)|((unsigned)h2u(h1)<<16);
              ph.y = (unsigned)h2u(h2)|((unsigned)h2u(h3)<<16);
    uint2 pl; pl.x = pk2h(l0,l1); pl.y = pk2h(l2,l3);
    *(uint2*)(Xh + off) = ph;
    *(uint2*)(Xl + off) = pl;
    float ssq = xv.x*xv.x + xv.y*xv.y + xv.z*xv.z + xv.w*xv.w;
    ssq += __shfl_xor(ssq, 1); ssq += __shfl_xor(ssq, 2);
    ssq += __shfl_xor(ssq, 4); ssq += __shfl_xor(ssq, 8);
    if ((tid & 15) == 0) dsm[row] = ssq;
  }
  __syncthreads();

  f16x8 ah[4], al[4];
  #pragma unroll
  for (int ks = 0; ks < 4; ++ks){
    int rgn = (wr*4+ks)*2+half;
    int off = rgn*512 + ((l31 ^ ((2*ks+half)<<2)))*16;
    ah[ks] = *(const f16x8*)(Xh + off);
    al[ks] = *(const f16x8*)(Xl + off);
  }
  f32x16 acc[4];
  #pragma unroll
  for (int ct=0; ct<4; ++ct){
    #pragma unroll
    for (int r=0; r<16; ++r) acc[ct][r] = 0.f;
  }
  #pragma unroll
  for (int ks = 0; ks < 4; ++ks){
    #pragma unroll
    for (int ct=0; ct<4; ++ct){
      int ctg = wc*4 + ct;
      int rgn = (ctg*4+ks)*2+half;
      f16x8 bv = *(const f16x8*)(Bp + rgn*512 + ((l31 ^ ((2*ks+half)<<2)))*16);
      acc[ct] = __builtin_amdgcn_mfma_f32_32x32x16_f16(ah[ks], bv, acc[ct], 0, 0, 0);
      acc[ct] = __builtin_amdgcn_mfma_f32_32x32x16_f16(al[ks], bv, acc[ct], 0, 0, 0);
    }
  }

  // per-row max over this wave's 128 cols
  float rmax[16];
  #pragma unroll
  for (int r=0; r<16; ++r){
    float mx = acc[0][r];
    #pragma unroll
    for (int ct=1; ct<4; ++ct) mx = fmaxf(mx, acc[ct][r]);
    #pragma unroll
    for (int s=1; s<32; s<<=1) mx = fmaxf(mx, __shfl_xor(mx, s));
    rmax[r] = mx;
  }
  if (isQ){
    if (l31 == 0){
      #pragma unroll
      for (int r=0; r<16; ++r)
        rmx[wc*128 + 32*wr + (r&3) + 8*(r>>2) + 4*half] = rmax[r];
    }
  } else {
    float wm = rmax[0];
    #pragma unroll
    for (int r=1; r<16; ++r) wm = fmaxf(wm, rmax[r]);
    wm = fmaxf(wm, __shfl_xor(wm, 32));
    if (lane == 0) wred[w] = wm;
  }
  __syncthreads();

  float lmb = 0.f;
  if (!isQ){
    lmb = wred[0];
    #pragma unroll
    for (int i=1;i<8;++i) lmb = fmaxf(lmb, wred[i]);
    if (tid == 0){
      lmArr[tile] = lmb;
      atomicMax(kmax, enc_f(lmb));
    }
  }
  float dgv[16], stv[16];
  #pragma unroll
  for (int r=0; r<16; ++r){
    int lrow = 32*wr + (r&3) + 8*(r>>2) + 4*half;
    dgv[r] = DIAGC * dsm[lrow];
    stv[r] = isQ ? fmaxf(rmx[lrow], rmx[128+lrow]) : lmb;
  }

  char* ob = sm;   // [128 rows][512B], swizzle ^((row&15)<<4); overwrites Bp/Xh/Xl
  #pragma unroll
  for (int r=0; r<16; ++r){
    int lrow = 32*wr + (r&3) + 8*(r>>2) + 4*half;
    #pragma unroll
    for (int ct=0; ct<4; ++ct){
      int col = wc*128 + ct*32 + l31;
      float e = __expf(acc[ct][r] - dgv[r] - stv[r]);
      float val = isQ ? RATIO*(e + KEPS) : e;
      *(ushort_t*)(ob + lrow*512 + ((col*2) ^ ((lrow&15)<<4))) = f2bf(val);
    }
  }
  __syncthreads();
  ushort_t* dst = (isQ ? qf : kfp) + (size_t)row0*256;
  for (int i = tid; i < 4096; i += 512){
    int row = i >> 5, s = i & 31;
    uint4 d = *(const uint4*)(ob + row*512 + ((s*16) ^ ((row&15)<<4)));
    *(uint4*)(dst + (size_t)row*256 + ((s ^ (row&15)))*8) = d;
  }
}

// K3 (MFMA): per-chunk sums on corrected kf = alpha*kfpre + kappa (applied at staging).
__launch_bounds__(256)
__global__ void k_chunk(const ushort_t* __restrict__ kfp, const float* __restrict__ v,
                        float* __restrict__ Zl, float* __restrict__ Sl,
                        const float* __restrict__ lmArr, const unsigned* __restrict__ kmax){
  extern __shared__ char sm[];
  char* kT = sm;            // [256 m][256 B]  (c 0..127 bf16)
  char* vT = sm + 65536;    // [64 e][256 B]
  int tid = threadIdx.x;
  int w   = tid >> 6;
  int lane= tid & 63;
  int l31 = lane & 31;
  int half= lane >> 5;
  int bh = blockIdx.x >> 5, j = blockIdx.x & 31;
  int row0 = bh*4096 + j*128;
  int cb = bh*32 + j;

  float gmv = dec_f(*kmax);
  float alpha = RATIO * __expf(lmArr[cb] - gmv);

  {
    const ushort_t* kp = kfp + (size_t)row0*256 + tid;
    char* krow = kT + tid*256;
    int swz = (tid & 15) << 4;
    #pragma unroll 16
    for (int c=0; c<128; ++c){
      float val = fmaf(alpha, bf2f(kp[(size_t)c*256]), KAPPA);
      *(ushort_t*)(krow + ((c*2) ^ swz)) = f2bf(val);
    }
  }
  {
    int e = tid & 63; int c0 = tid >> 6;
    char* vrow = vT + e*256;
    int swz = (e & 15) << 4;
    #pragma unroll 8
    for (int u=0; u<32; ++u){
      int c = c0 + u*4;
      float vv = v[(size_t)(row0+c)*64 + e];
      *(ushort_t*)(vrow + ((c*2) ^ swz)) = f2bf(vv);
    }
  }
  __syncthreads();

  f32x16 acc[2][2];
  f32x16 accz[2];
  #pragma unroll
  for (int a=0;a<2;++a){
    #pragma unroll
    for (int b=0;b<2;++b){
      #pragma unroll
      for (int r=0;r<16;++r) acc[a][b][r]=0.f;
    }
    #pragma unroll
    for (int r=0;r<16;++r) accz[a][r]=0.f;
  }
  bf16x8 onesf;
  #pragma unroll
  for (int i=0;i<8;++i) onesf[i] = (l31==0) ? (short)0x3F80 : (short)0;

  #pragma unroll
  for (int ks=0; ks<8; ++ks){
    int koff = ks*32 + half*16;
    bf16x8 af[2], bf[2];
    #pragma unroll
    for (int mt=0; mt<2; ++mt){
      int m = (2*w + mt)*32 + l31;
      af[mt] = *(const bf16x8*)(kT + m*256 + (koff ^ ((m&15)<<4)));
    }
    #pragma unroll
    for (int et=0; et<2; ++et){
      int e = et*32 + l31;
      bf[et] = *(const bf16x8*)(vT + e*256 + (koff ^ ((e&15)<<4)));
    }
    #pragma unroll
    for (int mt=0; mt<2; ++mt){
      accz[mt] = __builtin_amdgcn_mfma_f32_32x32x16_bf16(af[mt], onesf, accz[mt], 0, 0, 0);
      #pragma unroll
      for (int et=0; et<2; ++et)
        acc[mt][et] = __builtin_amdgcn_mfma_f32_32x32x16_bf16(af[mt], bf[et], acc[mt][et], 0, 0, 0);
    }
  }

  #pragma unroll
  for (int mt=0; mt<2; ++mt){
    #pragma unroll
    for (int r=0; r<16; ++r){
      int m = (2*w + mt)*32 + (r&3) + 8*(r>>2) + 4*half;
      #pragma unroll
      for (int et=0; et<2; ++et){
        int e = et*32 + l31;
        Sl[(size_t)cb*16384 + (size_t)m*64 + e] = acc[mt][et][r];
      }
    }
  }
  if (l31 == 0){
    #pragma unroll
    for (int mt=0; mt<2; ++mt){
      #pragma unroll
      for (int r=0; r<16; ++r){
        int m = (2*w + mt)*32 + (r&3) + 8*(r>>2) + 4*half;
        Zl[(size_t)cb*256 + m] = accz[mt][r];
      }
    }
  }
}

// K4: parallel exclusive scan over 32 chunks. Zl: excl in place + outZ.
// S: read Sl fp32, write S0b (bf16 exclusive, [cb][m][e]) + outS (fp32 inclusive).
__launch_bounds__(256)
__global__ void k_scan(float* __restrict__ Zl, const float* __restrict__ Sl,
                       ushort_t* __restrict__ S0b,
                       float* __restrict__ outZ, float* __restrict__ outS){
  int t = threadIdx.x;
  int bh = blockIdx.x / 65;
  int s  = blockIdx.x % 65;
  if (s == 64){
    size_t base = (size_t)(bh*32)*256 + t;
    float rz = 0.f;
    #pragma unroll
    for (int j0=0;j0<32;j0+=8){
      float x[8];
      #pragma unroll
      for (int u=0;u<8;++u) x[u] = Zl[base + (size_t)(j0+u)*256];
      #pragma unroll
      for (int u=0;u<8;++u){ Zl[base + (size_t)(j0+u)*256] = rz; rz += x[u]; }
    }
    outZ[(size_t)bh*256 + t] = rz;
  } else {
    size_t base = (size_t)(bh*32)*16384 + (size_t)s*256 + t;
    float rs = 0.f;
    #pragma unroll
    for (int j0=0;j0<32;j0+=8){
      float x[8];
      #pragma unroll
      for (int u=0;u<8;++u) x[u] = Sl[base + (size_t)(j0+u)*16384];
      #pragma unroll
      for (int u=0;u<8;++u){
        S0b[(size_t)(bh*32 + j0+u)*16384 + (size_t)s*256 + t] = f2bf(rs);
        rs += x[u];
      }
    }
    outS[(size_t)bh*16384 + (size_t)s*256 + t] = rs;
  }
}

// K5 (MFMA): per-chunk output; qz fused into qt staging; merged m-loop does
// A-part (qf*kf^T) and S0-part (qf*S0) off one staging; then A*v; divide.
__launch_bounds__(256)
__global__ void k_out(const ushort_t* __restrict__ qf, const ushort_t* __restrict__ kfp,
                      const float* __restrict__ v, const ushort_t* __restrict__ S0b,
                      const float* __restrict__ Zp, float* __restrict__ outO,
                      const float* __restrict__ lmArr, const unsigned* __restrict__ kmax){
  extern __shared__ char smc[];
  char* Ab  = smc;                  // [128][256B] bf16, swz ^((r&15)<<4)
  char* qtb = smc + 32768;          // [128][128B] bf16, swz ^((r&7)<<4)
  char* ktb = smc + 49152;          // [128][128B]
  char* s0t = smc + 65536;          // [64 e][128B], swz ^(((e&7)^((e>>3)&7))<<4)
  float* z0  = (float*)(smc + 73728);   // [256]
  float* qzl = (float*)(smc + 74752);   // [128]
  float* rsum= (float*)(smc + 75264);   // [128]

  int tid = threadIdx.x;
  int w   = tid >> 6;
  int lane= tid & 63;
  int l31 = lane & 31;
  int half= lane >> 5;
  int arow= 32*w + l31;
  int bh = blockIdx.x >> 5, j = blockIdx.x & 31;
  int row0 = bh*4096 + j*128;
  size_t qbase = (size_t)row0*256;
  int pb = bh*32 + j;

  float gmv = dec_f(*kmax);
  float alpha = RATIO * __expf(lmArr[pb] - gmv);

  z0[tid] = Zp[(size_t)pb*256 + tid] + AEPS;
  float qzp = 0.f;

  f32x16 acc[4];
  f32x16 acc2[2];
  #pragma unroll
  for (int ct=0;ct<4;++ct){
    #pragma unroll
    for (int r=0;r<16;++r) acc[ct][r] = 0.f;
  }
  #pragma unroll
  for (int et=0;et<2;++et){
    #pragma unroll
    for (int r=0;r<16;++r) acc2[et][r] = 0.f;
  }

  for (int m0=0;m0<256;m0+=64){
    __syncthreads();
    #pragma unroll
    for (int u=0;u<4;++u){
      int ci = tid*4+u; int rr = ci>>3, c8 = ci&7;
      int sw = (c8*16) ^ ((rr&7)<<4);
      uint4 rq = *(const uint4*)(qf + qbase + (size_t)rr*256 + m0 + c8*8);
      *(uint4*)(qtb + rr*128 + sw) = rq;
      float4 za = *(const float4*)&z0[m0 + c8*8];
      float4 zb = *(const float4*)&z0[m0 + c8*8 + 4];
      qzp += bf2f((ushort_t)(rq.x&0xffffu))*za.x + bf2f((ushort_t)(rq.x>>16))*za.y
           + bf2f((ushort_t)(rq.y&0xffffu))*za.z + bf2f((ushort_t)(rq.y>>16))*za.w
           + bf2f((ushort_t)(rq.z&0xffffu))*zb.x + bf2f((ushort_t)(rq.z>>16))*zb.y
           + bf2f((ushort_t)(rq.w&0xffffu))*zb.z + bf2f((ushort_t)(rq.w>>16))*zb.w;
      uint4 rk = *(const uint4*)(kfp + qbase + (size_t)rr*256 + m0 + c8*8);
      uint4 ck; ck.x = cvt2(rk.x, alpha); ck.y = cvt2(rk.y, alpha);
                ck.z = cvt2(rk.z, alpha); ck.w = cvt2(rk.w, alpha);
      *(uint4*)(ktb + rr*128 + sw) = ck;
    }
    #pragma unroll
    for (int u=0;u<2;++u){
      int idx = u*256 + tid; int mm = idx>>3, c8 = idx&7;
      uint4 sv = *(const uint4*)(S0b + (size_t)pb*16384 + (size_t)mm*64 + ((m0>>6)<<6)*0 + c8*8 + (size_t)0);
      (void)sv;
      // (placeholder removed below — real staging follows)
      break;
    }
    // s0t staging: S0b layout [pb][m][e]; bT[e][mm] = S0b[m0+mm][e]
    #pragma unroll
    for (int u=0;u<2;++u){
      int idx = u*256 + tid; int mm = idx>>3, c8 = idx&7;
      uint4 sv = *(const uint4*)(S0b + (size_t)pb*16384 + (size_t)(m0+mm)*64 + c8*8);
      unsigned wds[4] = {sv.x, sv.y, sv.z, sv.w};
      #pragma unroll
      for (int jj=0;jj<4;++jj){
        int e0 = c8*8 + jj*2;
        int e1 = e0 + 1;
        int sw0 = ((e0&7) ^ ((e0>>3)&7)) << 4;
        int sw1 = ((e1&7) ^ ((e1>>3)&7)) << 4;
        *(ushort_t*)(s0t + e0*128 + ((mm*2) ^ sw0)) = (ushort_t)(wds[jj] & 0xffffu);
        *(ushort_t*)(s0t + e1*128 + ((mm*2) ^ sw1)) = (ushort_t)(wds[jj] >> 16);
      }
    }
    __syncthreads();
    #pragma unroll
    for (int ks=0;ks<4;++ks){
      bf16x8 af = *(const bf16x8*)(qtb + arow*128 + ((ks*32 + half*16) ^ ((arow&7)<<4)));
      #pragma unroll
      for (int et=0;et<2;++et){
        int er = et*32 + l31;
        int sw = ((er&7) ^ ((er>>3)&7)) << 4;
        bf16x8 bS = *(const bf16x8*)(s0t + er*128 + ((ks*32 + half*16) ^ sw));
        acc2[et] = __builtin_amdgcn_mfma_f32_32x32x16_bf16(af, bS, acc2[et], 0, 0, 0);
      }
      #pragma unroll
      for (int ct=0;ct<4;++ct){
        if (ct <= w){
          int br = ct*32 + l31;
          bf16x8 bfv = *(const bf16x8*)(ktb + br*128 + ((ks*32 + half*16) ^ ((br&7)<<4)));
          acc[ct] = __builtin_amdgcn_mfma_f32_32x32x16_bf16(af, bfv, acc[ct], 0, 0, 0);
        }
      }
    }
  }

  // qz combine (threads tid, tid^1 share row tid>>1)
  qzp += __shfl_xor(qzp, 1);
  if ((tid & 1) == 0) qzl[tid>>1] = qzp;

  // A: mask, bf16 -> Ab, exact fp32 rowsums
  float p[16];
  #pragma unroll
  for (int r=0;r<16;++r) p[r]=0.f;
  #pragma unroll
  for (int ct=0;ct<4;++ct){
    #pragma unroll
    for (int r=0;r<16;++r){
      int grow = 32*w + (r&3) + 8*(r>>2) + 4*half;
      int col  = ct*32 + l31;
      float m = (col <= grow) ? acc[ct][r] : 0.f;
      p[r] += m;
      *(ushort_t*)(Ab + grow*256 + ((col*2) ^ ((grow&15)<<4))) = f2bf(m);
    }
  }
  #pragma unroll
  for (int s=1;s<32;s<<=1){
    #pragma unroll
    for (int r=0;r<16;++r) p[r] += __shfl_xor(p[r], s);
  }
  if (l31 == 0){
    #pragma unroll
    for (int r=0;r<16;++r) rsum[32*w + (r&3) + 8*(r>>2) + 4*half] = p[r];
  }
  __syncthreads();

  // A*v over 2 K=64 tiles (v bf16-staged into s0t region)
  for (int kt=0; kt<2; ++kt){
    #pragma unroll
    for (int u=0;u<4;++u){
      int idx = tid*4+u; int rr = idx>>4, c4 = idx&15;
      float4 vv = *(const float4*)&v[(size_t)(row0 + kt*64 + rr)*64 + c4*4];
      float vals[4] = {vv.x, vv.y, vv.z, vv.w};
      #pragma unroll
      for (int jj=0;jj<4;++jj){
        int e = c4*4 + jj;
        int sw = ((e&7) ^ ((e>>3)&7)) << 4;
        *(ushort_t*)(s0t + e*128 + ((rr*2) ^ sw)) = f2bf(vals[jj]);
      }
    }
    __syncthreads();
    #pragma unroll
    for (int ks=0;ks<4;++ks){
      if (kt*64 + ks*16 <= 32*w + 31){   // wave-uniform: A zero above diagonal
        bf16x8 af = *(const bf16x8*)(Ab + arow*256 + ((kt*128 + ks*32 + half*16) ^ ((arow&15)<<4)));
        #pragma unroll
        for (int et=0;et<2;++et){
          int er = et*32 + l31;
          int sw = ((er&7) ^ ((er>>3)&7)) << 4;
          bf16x8 bfv = *(const bf16x8*)(s0t + er*128 + ((ks*32 + half*16) ^ sw));
          acc2[et] = __builtin_amdgcn_mfma_f32_32x32x16_bf16(af, bfv, acc2[et], 0, 0, 0);
        }
      }
    }
    __syncthreads();
  }

  if (tid < 128) rsum[tid] = 1.0f / (rsum[tid] + qzl[tid]);
  __syncthreads();
  float dvv[16];
  #pragma unroll
  for (int r=0;r<16;++r) dvv[r] = rsum[32*w + (r&3) + 8*(r>>2) + 4*half];
  #pragma unroll
  for (int et=0;et<2;++et){
    #pragma unroll
    for (int r=0;r<16;++r){
      int qrow = 32*w + (r&3) + 8*(r>>2) + 4*half;
      int e = et*32 + l31;
      outO[(size_t)(row0+qrow)*64 + e] = acc2[et][r] * dvv[r];
    }
  }
}

extern "C" void kernel_launch(void* const* d_in, const int* in_sizes, int n_in,
                              void* d_out, int out_size, void* d_ws, size_t ws_size,
                              hipStream_t stream){
  (void)in_sizes; (void)n_in; (void)out_size; (void)ws_size;
  const float* q    = (const float*)d_in[0];
  const float* k    = (const float*)d_in[1];
  const float* v    = (const float*)d_in[2];
  const float* proj = (const float*)d_in[3];

  char* ws = (char*)d_ws;
  unsigned* kmax = (unsigned*)ws;                                   // @0
  float*    lmA  = (float*)(ws + 256);                              // 2048 B
  ushort_t* pjh  = (ushort_t*)(ws + 4096);                          // 32768 B
  ushort_t* qf   = (ushort_t*)(ws + 65792);                         // 33554432 B
  ushort_t* kfp  = (ushort_t*)(ws + 65792 + 33554432);              // 33554432 B
  float*    Zl   = (float*)(ws + 65792 + 67108864);                 // 524288 B
  float*    Sl   = (float*)(ws + 65792 + 67108864 + 524288);        // 33554432 B
  ushort_t* S0b  = (ushort_t*)(ws + 65792 + 67108864 + 524288 + 33554432); // 16777216 B

  float* outO = (float*)d_out;
  float* outZ = outO + (size_t)2*8*4096*64;
  float* outS = outZ + 2*8*256;

  hipFuncSetAttribute((const void*)k_feat,  hipFuncAttributeMaxDynamicSharedMemorySize, 67104);
  hipFuncSetAttribute((const void*)k_chunk, hipFuncAttributeMaxDynamicSharedMemorySize, 81920);
  hipFuncSetAttribute((const void*)k_out,   hipFuncAttributeMaxDynamicSharedMemorySize, 75776);

  k_prep <<<1,      256, 0, stream>>>(proj, pjh, kmax);
  k_feat <<<1024,   512, 67104, stream>>>(q, k, pjh, qf, kfp, kmax, lmA);
  k_chunk<<<512,    256, 81920, stream>>>(kfp, v, Zl, Sl, lmA, kmax);
  k_scan <<<16*65,  256, 0, stream>>>(Zl, Sl, S0b, outZ, outS);
  k_out  <<<512,    256, 75776, stream>>>(qf, kfp, v, S0b, Zl, outO, lmA, kmax);
}